// Round 11
// baseline (150.928 us; speedup 1.0000x reference)
//
#include <hip/hip_runtime.h>

#define SEQ   200
#define BATCH 1024
#define DIM   300
#define HID   600
#define VOCAB 100000

#define NSCH   2             // s-chunks per pass
#define SCH    (SEQ / NSCH)  // 100
#define RSPLIT 50000         // token-range split (2 passes x 120 MB working set)

#define BW    4              // batches per wave (mlp)
#define JCH   12             // j-chunks across blockIdx.y (mlp)
#define JPER  (HID / JCH)    // 50 j per chunk

#define HIDDEN_ELEMS (BATCH * HID)               // 614400
#define HIDDEN_BYTES ((size_t)HIDDEN_ELEMS * 4)  // 2,457,600

// ---------- Kernel 1: dedup + fp32 gather, token-range partitioned -------
// One dispatch per token-range half (so each dispatch's table working set
// is 120 MB -> L3-resident). Grid (1024 columns, 2 s-chunks) x 192 threads.
// Dedup mask scans the FULL prefix (global first-occurrence semantics);
// the gather branch (keep && in-range) is wave-uniform (same s for all
// lanes) -> skipped rows cost only a scalar branch, no wasted loads.
__global__ __launch_bounds__(192) void embed_part_kernel(
    const int* __restrict__ tokens,
    const float* __restrict__ lut,
    const float* __restrict__ slut,
    float* __restrict__ hid4,
    int lo, int hi, int qbase) {
  const int b   = blockIdx.x;
  const int sc  = blockIdx.y;
  const int tid = threadIdx.x;

  __shared__ int   toks[SEQ];
  __shared__ float keep[SCH];

  for (int s = tid; s < SEQ; s += 192) toks[s] = tokens[s * BATCH + b];
  __syncthreads();

  const int s0 = sc * SCH;
  if (tid < SCH) {
    const int s = s0 + tid;
    const int t = toks[s];
    float m = 1.f;
    for (int p = 0; p < s; ++p) {        // full-prefix scan: dedup is global
      if (toks[p] == t) { m = 0.f; break; }
    }
    keep[tid] = m;
  }
  __syncthreads();

  const int tab_i = tid / 75;            // 0 -> lut, 1 -> slut, 2 -> idle
  const int slot  = tid % 75;            // float4 slice of the 300-float row
  if (tab_i < 2) {
    const float* __restrict__ tab = tab_i ? slut : lut;
    float4 a = make_float4(0.f, 0.f, 0.f, 0.f);
    for (int i = 0; i < SCH; ++i) {
      const int t = toks[s0 + i];
      // wave-uniform condition: same s for every lane of the wave
      if ((keep[i] != 0.f) & (t >= lo) & (t < hi)) {
        const float4 v = ((const float4*)(tab + (size_t)t * DIM))[slot];
        a.x += v.x; a.y += v.y; a.z += v.z; a.w += v.w;
      }
    }
    float* dst = hid4 + ((size_t)(qbase + sc) * BATCH + b) * HID + tab_i * DIM;
    ((float4*)dst)[slot] = a;
  }
}

// ---------- Kernel 1b: hidden = sum of 4 partials ------------------------
__global__ __launch_bounds__(256) void combine_kernel(
    const float* __restrict__ hid4, float* __restrict__ hidden) {
  const int i = blockIdx.x * 256 + threadIdx.x;   // float4 index
  const int n4 = HIDDEN_ELEMS / 4;                // 153600
  if (i < n4) {
    const float4* p = (const float4*)hid4;
    const float4 a = p[i];
    const float4 b = p[i + n4];
    const float4 c = p[i + 2 * n4];
    const float4 d = p[i + 3 * n4];
    float4 s;
    s.x = (a.x + b.x) + (c.x + d.x);
    s.y = (a.y + b.y) + (c.y + d.y);
    s.z = (a.z + b.z) + (c.z + d.z);
    s.w = (a.w + b.w) + (c.w + d.w);
    ((float4*)hidden)[i] = s;
  }
}

// ---------- Kernel 2a: out[b] = b2 ---------------------------------------
__global__ __launch_bounds__(256) void out_init_kernel(
    float* __restrict__ out, const float* __restrict__ b2) {
  const int i = blockIdx.x * 256 + threadIdx.x;
  if (i < BATCH) out[i] = b2[0];
}

// ---------- Kernel 2b: MLP — 4 batches/wave, W1 reused 4x, DPP reduce ----
template <int CTRL>
__device__ __forceinline__ float dpp_add(float x) {
  const int y = __builtin_amdgcn_update_dpp(
      0, __float_as_int(x), CTRL, 0xf, 0xf, true);
  return x + __int_as_float(y);
}

__device__ __forceinline__ float wave_sum(float h) {
  h = dpp_add<0x111>(h);   // row_shr:1
  h = dpp_add<0x112>(h);   // row_shr:2
  h = dpp_add<0x114>(h);   // row_shr:4
  h = dpp_add<0x118>(h);   // row_shr:8
  h = dpp_add<0x142>(h);   // row_bcast:15
  h = dpp_add<0x143>(h);   // row_bcast:31  -> lane 63 holds full sum
  return h;
}

__global__ __launch_bounds__(256) void mlp_kernel(
    const float* __restrict__ hidden,
    const float* __restrict__ W1,
    const float* __restrict__ b1,
    const float* __restrict__ W2,
    float* __restrict__ out) {
  const int wave = threadIdx.x >> 6;
  const int lane = threadIdx.x & 63;
  const int b0   = (blockIdx.x * 4 + wave) * BW;
  const int j0   = blockIdx.y * JPER;

  // preload 4 hidden rows: k = lane + 64*i (600 = 64*9 + 24)
  float a[BW][10];
#pragma unroll
  for (int bb = 0; bb < BW; ++bb) {
    const float* __restrict__ hb = hidden + (size_t)(b0 + bb) * HID;
#pragma unroll
    for (int i = 0; i < 9; ++i) a[bb][i] = hb[lane + 64 * i];
    a[bb][9] = (lane < 24) ? hb[lane + 576] : 0.f;
  }

  float acc[BW] = {0.f, 0.f, 0.f, 0.f};

#pragma unroll 2
  for (int jj = 0; jj < JPER; ++jj) {
    const int j = j0 + jj;
    const float* __restrict__ wr = W1 + (size_t)j * HID;
    float d0 = 0.f, d1 = 0.f, d2 = 0.f, d3 = 0.f;
#pragma unroll
    for (int i = 0; i < 9; ++i) {
      const float w = wr[lane + 64 * i];
      d0 += a[0][i] * w;
      d1 += a[1][i] * w;
      d2 += a[2][i] * w;
      d3 += a[3][i] * w;
    }
    {
      const float w = (lane < 24) ? wr[lane + 576] : 0.f;
      d0 += a[0][9] * w;
      d1 += a[1][9] * w;
      d2 += a[2][9] * w;
      d3 += a[3][9] * w;
    }
    // 4 independent 6-step DPP chains (ILP hides DPP latency)
    d0 = wave_sum(d0); d1 = wave_sum(d1);
    d2 = wave_sum(d2); d3 = wave_sum(d3);
    // branch-free epilogue: only lane 63's acc is ever consumed
    const float b1j = b1[j];
    const float w2j = W2[j];
    acc[0] += fmaxf(d0 + b1j, 0.f) * w2j;
    acc[1] += fmaxf(d1 + b1j, 0.f) * w2j;
    acc[2] += fmaxf(d2 + b1j, 0.f) * w2j;
    acc[3] += fmaxf(d3 + b1j, 0.f) * w2j;
  }

  if (lane == 63) {
#pragma unroll
    for (int bb = 0; bb < BW; ++bb) atomicAdd(&out[b0 + bb], acc[bb]);
  }
}

extern "C" void kernel_launch(void* const* d_in, const int* in_sizes, int n_in,
                              void* d_out, int out_size, void* d_ws, size_t ws_size,
                              hipStream_t stream) {
  const int*   tokens = (const int*)  d_in[0];
  const float* lut    = (const float*)d_in[1];
  const float* slut   = (const float*)d_in[2];
  const float* W1     = (const float*)d_in[3];
  const float* b1     = (const float*)d_in[4];
  const float* W2     = (const float*)d_in[5];
  const float* b2     = (const float*)d_in[6];
  float* out = (float*)d_out;

  float* hid4   = (float*)d_ws;                                 // 4 x 2.4 MB
  float* hidden = (float*)((char*)d_ws + 4 * HIDDEN_BYTES);

  out_init_kernel<<<(BATCH + 255) / 256, 256, 0, stream>>>(out, b2);
  // pass 0: table rows v in [0, 50000)  -> 120 MB working set (L3-fit)
  embed_part_kernel<<<dim3(BATCH, NSCH), 192, 0, stream>>>(
      tokens, lut, slut, hid4, 0, RSPLIT, 0);
  // pass 1: table rows v in [50000, 100000)
  embed_part_kernel<<<dim3(BATCH, NSCH), 192, 0, stream>>>(
      tokens, lut, slut, hid4, RSPLIT, VOCAB, 2);
  combine_kernel<<<(HIDDEN_ELEMS / 4 + 255) / 256, 256, 0, stream>>>(
      hid4, hidden);
  mlp_kernel<<<dim3(BATCH / (4 * BW), JCH), 256, 0, stream>>>(
      hidden, W1, b1, W2, out);
}

// Round 12
// 128.950 us; speedup vs baseline: 1.1704x; 1.1704x over previous
//
#include <hip/hip_runtime.h>
#include <limits.h>

#define SEQ   200
#define BATCH 1024
#define DIM   300
#define HID   600
#define VOCAB 100000

#define NQ    4              // sorted-list quarters (grid.y)

#define BW    4              // batches per wave (mlp)
#define JCH   12             // j-chunks across blockIdx.y (mlp)
#define JPER  (HID / JCH)    // 50 j per chunk

#define HIDDEN_ELEMS (BATCH * HID)               // 614400
#define HIDDEN_BYTES ((size_t)HIDDEN_ELEMS * 4)  // 2,457,600

// ---------- Kernel 1: dedup + SORTED fp32 gather -------------------------
// One block per (column, quarter). Dedup keeps first occurrences, bitonic-
// sorts the ~196 unique tokens ascending in LDS (dupes -> INT_MAX sink),
// then gathers quarter q of the sorted list: row addresses monotonically
// increase -> page-sequential translation + near-sequential DRAM/fabric
// access. Partial sums -> hid4[q][b][600]; combine_kernel reduces.
__global__ __launch_bounds__(256) void embed_sort_kernel(
    const int* __restrict__ tokens,
    const float* __restrict__ lut,
    const float* __restrict__ slut,
    float* __restrict__ hid4) {
  const int b   = blockIdx.x;
  const int q   = blockIdx.y;
  const int tid = threadIdx.x;

  __shared__ int toks[SEQ];
  __shared__ int stok[256];
  __shared__ int nk_sh;

  for (int s = tid; s < SEQ; s += 256) toks[s] = tokens[s * BATCH + b];
  if (tid == 0) nk_sh = 0;
  __syncthreads();

  // first-occurrence dedup; non-kept and pad slots -> INT_MAX
  int my = INT_MAX;
  if (tid < SEQ) {
    const int t = toks[tid];
    bool k = true;
    for (int p = 0; p < tid; ++p) {
      if (toks[p] == t) { k = false; break; }
    }
    if (k) my = t;
  }
  stok[tid] = my;
  if (my != INT_MAX) atomicAdd(&nk_sh, 1);
  __syncthreads();

  // bitonic sort, 256 elements ascending (INT_MAX sinks to the tail)
  for (int k = 2; k <= 256; k <<= 1) {
    for (int j = k >> 1; j > 0; j >>= 1) {
      const int ixj = tid ^ j;
      if (ixj > tid) {
        const int a = stok[tid];
        const int c = stok[ixj];
        const bool up = ((tid & k) == 0);
        if ((a > c) == up) { stok[tid] = c; stok[ixj] = a; }
      }
      __syncthreads();
    }
  }

  const int nk = nk_sh;
  const int i0 = (q * nk) / NQ;
  const int i1 = ((q + 1) * nk) / NQ;

  const int tab_i = tid / 75;            // 0 -> lut, 1 -> slut, >=2 -> idle
  const int slot  = tid % 75;            // float4 slice of the 300-float row
  if (tab_i < 2) {
    const float* __restrict__ tab = tab_i ? slut : lut;
    float4 a = make_float4(0.f, 0.f, 0.f, 0.f);
#pragma unroll 4
    for (int i = i0; i < i1; ++i) {      // ascending row ids
      const float4 v = ((const float4*)(tab + (size_t)stok[i] * DIM))[slot];
      a.x += v.x; a.y += v.y; a.z += v.z; a.w += v.w;
    }
    float* dst = hid4 + ((size_t)q * BATCH + b) * HID + tab_i * DIM;
    ((float4*)dst)[slot] = a;
  }
}

// ---------- Kernel 1b: hidden = sum of 4 partials ------------------------
__global__ __launch_bounds__(256) void combine_kernel(
    const float* __restrict__ hid4, float* __restrict__ hidden) {
  const int i = blockIdx.x * 256 + threadIdx.x;   // float4 index
  const int n4 = HIDDEN_ELEMS / 4;                // 153600
  if (i < n4) {
    const float4* p = (const float4*)hid4;
    const float4 a = p[i];
    const float4 b = p[i + n4];
    const float4 c = p[i + 2 * n4];
    const float4 d = p[i + 3 * n4];
    float4 s;
    s.x = (a.x + b.x) + (c.x + d.x);
    s.y = (a.y + b.y) + (c.y + d.y);
    s.z = (a.z + b.z) + (c.z + d.z);
    s.w = (a.w + b.w) + (c.w + d.w);
    ((float4*)hidden)[i] = s;
  }
}

// ---------- Kernel 2a: out[b] = b2 ---------------------------------------
__global__ __launch_bounds__(256) void out_init_kernel(
    float* __restrict__ out, const float* __restrict__ b2) {
  const int i = blockIdx.x * 256 + threadIdx.x;
  if (i < BATCH) out[i] = b2[0];
}

// ---------- Kernel 2b: MLP — 4 batches/wave, W1 reused 4x, DPP reduce ----
template <int CTRL>
__device__ __forceinline__ float dpp_add(float x) {
  const int y = __builtin_amdgcn_update_dpp(
      0, __float_as_int(x), CTRL, 0xf, 0xf, true);
  return x + __int_as_float(y);
}

__device__ __forceinline__ float wave_sum(float h) {
  h = dpp_add<0x111>(h);   // row_shr:1
  h = dpp_add<0x112>(h);   // row_shr:2
  h = dpp_add<0x114>(h);   // row_shr:4
  h = dpp_add<0x118>(h);   // row_shr:8
  h = dpp_add<0x142>(h);   // row_bcast:15
  h = dpp_add<0x143>(h);   // row_bcast:31  -> lane 63 holds full sum
  return h;
}

__global__ __launch_bounds__(256) void mlp_kernel(
    const float* __restrict__ hidden,
    const float* __restrict__ W1,
    const float* __restrict__ b1,
    const float* __restrict__ W2,
    float* __restrict__ out) {
  const int wave = threadIdx.x >> 6;
  const int lane = threadIdx.x & 63;
  const int b0   = (blockIdx.x * 4 + wave) * BW;
  const int j0   = blockIdx.y * JPER;

  // preload 4 hidden rows: k = lane + 64*i (600 = 64*9 + 24)
  float a[BW][10];
#pragma unroll
  for (int bb = 0; bb < BW; ++bb) {
    const float* __restrict__ hb = hidden + (size_t)(b0 + bb) * HID;
#pragma unroll
    for (int i = 0; i < 9; ++i) a[bb][i] = hb[lane + 64 * i];
    a[bb][9] = (lane < 24) ? hb[lane + 576] : 0.f;
  }

  float acc[BW] = {0.f, 0.f, 0.f, 0.f};

#pragma unroll 2
  for (int jj = 0; jj < JPER; ++jj) {
    const int j = j0 + jj;
    const float* __restrict__ wr = W1 + (size_t)j * HID;
    float d0 = 0.f, d1 = 0.f, d2 = 0.f, d3 = 0.f;
#pragma unroll
    for (int i = 0; i < 9; ++i) {
      const float w = wr[lane + 64 * i];
      d0 += a[0][i] * w;
      d1 += a[1][i] * w;
      d2 += a[2][i] * w;
      d3 += a[3][i] * w;
    }
    {
      const float w = (lane < 24) ? wr[lane + 576] : 0.f;
      d0 += a[0][9] * w;
      d1 += a[1][9] * w;
      d2 += a[2][9] * w;
      d3 += a[3][9] * w;
    }
    // 4 independent 6-step DPP chains (ILP hides DPP latency)
    d0 = wave_sum(d0); d1 = wave_sum(d1);
    d2 = wave_sum(d2); d3 = wave_sum(d3);
    // branch-free epilogue: only lane 63's acc is ever consumed
    const float b1j = b1[j];
    const float w2j = W2[j];
    acc[0] += fmaxf(d0 + b1j, 0.f) * w2j;
    acc[1] += fmaxf(d1 + b1j, 0.f) * w2j;
    acc[2] += fmaxf(d2 + b1j, 0.f) * w2j;
    acc[3] += fmaxf(d3 + b1j, 0.f) * w2j;
  }

  if (lane == 63) {
#pragma unroll
    for (int bb = 0; bb < BW; ++bb) atomicAdd(&out[b0 + bb], acc[bb]);
  }
}

extern "C" void kernel_launch(void* const* d_in, const int* in_sizes, int n_in,
                              void* d_out, int out_size, void* d_ws, size_t ws_size,
                              hipStream_t stream) {
  const int*   tokens = (const int*)  d_in[0];
  const float* lut    = (const float*)d_in[1];
  const float* slut   = (const float*)d_in[2];
  const float* W1     = (const float*)d_in[3];
  const float* b1     = (const float*)d_in[4];
  const float* W2     = (const float*)d_in[5];
  const float* b2     = (const float*)d_in[6];
  float* out = (float*)d_out;

  float* hid4   = (float*)d_ws;                                 // 4 x 2.4 MB
  float* hidden = (float*)((char*)d_ws + 4 * HIDDEN_BYTES);

  out_init_kernel<<<(BATCH + 255) / 256, 256, 0, stream>>>(out, b2);
  embed_sort_kernel<<<dim3(BATCH, NQ), 256, 0, stream>>>(
      tokens, lut, slut, hid4);
  combine_kernel<<<(HIDDEN_ELEMS / 4 + 255) / 256, 256, 0, stream>>>(
      hid4, hidden);
  mlp_kernel<<<dim3(BATCH / (4 * BW), JCH), 256, 0, stream>>>(
      hidden, W1, b1, W2, out);
}